// Round 5
// baseline (104.487 us; speedup 1.0000x reference)
//
#include <hip/hip_runtime.h>

// B=16384, DIM=64, 8 coupling steps, H=8, D2=32.
// y = J^{-1} g applied analytically (triangular coupling blocks -> MLP JVPs);
// intermediate states recovered by inverting the flow from z = phi(x).
//
// R15 = R14 with scratch FULLY eliminated. R14 removed the pointer-selects
// (WRITE_SIZE 32.3->27.1 MB, 69->43 us) but kept float t8[8]/s8[8]/ut8[8]/
// us8[8] arrays indexed by j-loop vars inside pragma-unroll loops. SROA runs
// BEFORE unrolling folds j to constants -> those arrays are allocas ->
// ~23 MiB/dispatch of scratch evictions on the serial chain (and the ~180 B
// of stack/thread explains VGPR_Count pinned at 128). R15 scalarizes EVERY
// local array into named scalars via token-pasting macros: zero indexed
// local storage in the IR, state is pure SSA.
// Layout identity (gfx950, verified m89): D (col=lane&15,row=4q+reg) ==
// B-operand (n=lane&15,k=4q+j) for K=16 -> tanh(D)->pack is per-lane, zero
// cross-lane ops.

namespace {

typedef __fp16 f16x2 __attribute__((ext_vector_type(2)));
typedef __fp16 v4h __attribute__((ext_vector_type(4)));
typedef __fp16 v8h __attribute__((ext_vector_type(8)));
typedef float f32x4 __attribute__((ext_vector_type(4)));

constexpr int NB = 16384;

__device__ __forceinline__ float frcp(float x) { return __builtin_amdgcn_rcpf(x); }
__device__ __forceinline__ float ftanh(float x) {
  float e = __expf(2.f * x);
  return 1.f - 2.f * frcp(e + 1.f);
}
__device__ __forceinline__ f16x2 pk(float a, float b) {
  return __builtin_amdgcn_cvt_pkrtz(a, b);
}

union U8 { v8h v; f16x2 h[4]; float4 f4; };
union U4 { v4h v; f16x2 h[2]; float2 f2; };

// net pair p (0..15): step i = p>>1, half = p&1 -> t-net base.
__device__ __forceinline__ int pbase(int p) {
  return ((p >> 1) << 2) + ((p & 1) << 1);
}

}  // namespace

// ---- forward L3 block: one output quad -> four named scalars ----
#define L3_FWD(P, BB, D0, D1, D2, D3)                                         \
  do {                                                                        \
    const bool act_ = ((BB) < 2) == (q < 2);                                  \
    v4h Ab = *(const v4h*)(LW2 + ((P)*256 + (BB)*64 + abbase));               \
    Ab = act_ ? Ab : z4;                                                      \
    const f32x4 cb = *(const f32x4*)(LB2 + ((P)*4 + (BB)) * 16 + q * 4);      \
    const f32x4 ob =                                                          \
        __builtin_amdgcn_mfma_f32_16x16x16f16(Ab, H2.v, cb, 0, 0, 0);         \
    D0 = ob[0]; D1 = ob[1]; D2 = ob[2]; D3 = ob[3];                           \
  } while (0)

#define FWD_UPD(J, W) W##J = fmaf(W##J, __expf(s##J), t##J)

// ---- forward half-step P: reads V0..V7 (prefix V), updates W0..W7 ----
#define FWD_HALF(P, V, W)                                                     \
  do {                                                                        \
    U8 Bq;                                                                    \
    Bq.h[0] = pk(V##0, V##1);                                                 \
    Bq.h[1] = pk(V##2, V##3);                                                 \
    Bq.h[2] = pk(V##4, V##5);                                                 \
    Bq.h[3] = pk(V##6, V##7);                                                 \
    const v8h A0 = *(const v8h*)(LW0 + (((P)*64 + q * 16 + n) << 2));         \
    const f32x4 c0 = *(const f32x4*)(LB0 + (P)*16 + q * 4);                   \
    f32x4 d1 = __builtin_amdgcn_mfma_f32_16x16x32_f16(A0, Bq.v, c0, 0, 0, 0); \
    U4 H1;                                                                    \
    H1.h[0] = pk(ftanh(d1[0]), ftanh(d1[1]));                                 \
    H1.h[1] = pk(ftanh(d1[2]), ftanh(d1[3]));                                 \
    v4h A1 = *(const v4h*)(LW1 + ((P)*64 + a1off));                           \
    A1 = act1 ? A1 : z4;                                                      \
    const f32x4 c1 = *(const f32x4*)(LB1 + (P)*16 + q * 4);                   \
    f32x4 d2 = __builtin_amdgcn_mfma_f32_16x16x16f16(A1, H1.v, c1, 0, 0, 0);  \
    U4 H2;                                                                    \
    H2.h[0] = pk(ftanh(d2[0]), ftanh(d2[1]));                                 \
    H2.h[1] = pk(ftanh(d2[2]), ftanh(d2[3]));                                 \
    if (n < 8) {                                                              \
      float4 pkd;                                                             \
      pkd.x = __builtin_bit_cast(float, H1.h[0]);                             \
      pkd.y = __builtin_bit_cast(float, H1.h[1]);                             \
      pkd.z = __builtin_bit_cast(float, H2.h[0]);                             \
      pkd.w = __builtin_bit_cast(float, H2.h[1]);                             \
      sHC[(P)*128 + hcb] = pkd;                                               \
    }                                                                         \
    float t0, t1, t2, t3, t4, t5, t6, t7;                                     \
    float s0, s1, s2, s3, s4, s5, s6, s7;                                     \
    L3_FWD(P, 0, t0, t1, t2, t3);                                             \
    L3_FWD(P, 1, t4, t5, t6, t7);                                             \
    L3_FWD(P, 2, s0, s1, s2, s3);                                             \
    L3_FWD(P, 3, s4, s5, s6, s7);                                             \
    FWD_UPD(0, W); FWD_UPD(1, W); FWD_UPD(2, W); FWD_UPD(3, W);               \
    FWD_UPD(4, W); FWD_UPD(5, W); FWD_UPD(6, W); FWD_UPD(7, W);               \
  } while (0)

// ---- backward L3 block: t/s recompute + JVP -> eight named scalars ----
#define L3_BWD(P, BB, D0, D1, D2, D3, J0, J1, J2, J3)                         \
  do {                                                                        \
    const bool act_ = ((BB) < 2) == (q < 2);                                  \
    v4h Ab = *(const v4h*)(LW2 + ((P)*256 + (BB)*64 + abbase));               \
    Ab = act_ ? Ab : z4;                                                      \
    const f32x4 cb = *(const f32x4*)(LB2 + ((P)*4 + (BB)) * 16 + q * 4);      \
    const f32x4 ob =                                                          \
        __builtin_amdgcn_mfma_f32_16x16x16f16(Ab, H2.v, cb, 0, 0, 0);         \
    const f32x4 jb =                                                          \
        __builtin_amdgcn_mfma_f32_16x16x16f16(Ab, G2.v, zc, 0, 0, 0);         \
    D0 = ob[0]; D1 = ob[1]; D2 = ob[2]; D3 = ob[3];                           \
    J0 = jb[0]; J1 = jb[1]; J2 = jb[2]; J3 = jb[3];                           \
  } while (0)

#define BWD_INV(J, ST, DME)                                                   \
  do {                                                                        \
    const float esi_ = __expf(-s##J);                                         \
    const float dd_ = ST##J - t##J;                                           \
    ST##J = dd_ * esi_;                                                       \
    DME##J = (DME##J - ut##J - dd_ * us##J) * esi_;                           \
  } while (0)

// ---- backward half-step P: inverts ST0..7, updates duals DME0..7 from DOT ----
#define BWD_HALF(P, ST, DME, DOT)                                             \
  do {                                                                        \
    U4 H1, H2;                                                                \
    {                                                                         \
      const float4 pkd = sHC[(P)*128 + hcb];                                  \
      H1.h[0] = __builtin_bit_cast(f16x2, pkd.x);                             \
      H1.h[1] = __builtin_bit_cast(f16x2, pkd.y);                             \
      H2.h[0] = __builtin_bit_cast(f16x2, pkd.z);                             \
      H2.h[1] = __builtin_bit_cast(f16x2, pkd.w);                             \
    }                                                                         \
    U8 Bu;                                                                    \
    Bu.h[0] = pk(DOT##0, DOT##1);                                             \
    Bu.h[1] = pk(DOT##2, DOT##3);                                             \
    Bu.h[2] = pk(DOT##4, DOT##5);                                             \
    Bu.h[3] = pk(DOT##6, DOT##7);                                             \
    const v8h A0 = *(const v8h*)(LW0 + (((P)*64 + q * 16 + n) << 2));         \
    f32x4 d1u =                                                               \
        __builtin_amdgcn_mfma_f32_16x16x32_f16(A0, Bu.v, zc, 0, 0, 0);        \
    U4 G1;                                                                    \
    {                                                                         \
      const float ha = (float)H1.v[0], hb = (float)H1.v[1];                   \
      const float hc = (float)H1.v[2], hd = (float)H1.v[3];                   \
      G1.h[0] = pk((1.f - ha * ha) * d1u[0], (1.f - hb * hb) * d1u[1]);       \
      G1.h[1] = pk((1.f - hc * hc) * d1u[2], (1.f - hd * hd) * d1u[3]);       \
    }                                                                         \
    v4h A1 = *(const v4h*)(LW1 + ((P)*64 + a1off));                           \
    A1 = act1 ? A1 : z4;                                                      \
    f32x4 d2u =                                                               \
        __builtin_amdgcn_mfma_f32_16x16x16f16(A1, G1.v, zc, 0, 0, 0);         \
    U4 G2;                                                                    \
    {                                                                         \
      const float ha = (float)H2.v[0], hb = (float)H2.v[1];                   \
      const float hc = (float)H2.v[2], hd = (float)H2.v[3];                   \
      G2.h[0] = pk((1.f - ha * ha) * d2u[0], (1.f - hb * hb) * d2u[1]);       \
      G2.h[1] = pk((1.f - hc * hc) * d2u[2], (1.f - hd * hd) * d2u[3]);       \
    }                                                                         \
    float t0, t1, t2, t3, t4, t5, t6, t7;                                     \
    float s0, s1, s2, s3, s4, s5, s6, s7;                                     \
    float ut0, ut1, ut2, ut3, ut4, ut5, ut6, ut7;                             \
    float us0, us1, us2, us3, us4, us5, us6, us7;                             \
    L3_BWD(P, 0, t0, t1, t2, t3, ut0, ut1, ut2, ut3);                         \
    L3_BWD(P, 1, t4, t5, t6, t7, ut4, ut5, ut6, ut7);                         \
    L3_BWD(P, 2, s0, s1, s2, s3, us0, us1, us2, us3);                         \
    L3_BWD(P, 3, s4, s5, s6, s7, us4, us5, us6, us7);                         \
    BWD_INV(0, ST, DME); BWD_INV(1, ST, DME);                                 \
    BWD_INV(2, ST, DME); BWD_INV(3, ST, DME);                                 \
    BWD_INV(4, ST, DME); BWD_INV(5, ST, DME);                                 \
    BWD_INV(6, ST, DME); BWD_INV(7, ST, DME);                                 \
  } while (0)

// 256 threads = 4 waves = 32 elements/block (8/wave, mirrored), grid 512 ->
// 2048 waves = 2/SIMD, 2 blocks/CU. LDS: 42 KiB weights + 32 KiB H-cache =
// 74 KiB (<80 KiB so two blocks co-reside). waves_per_eu pinned (2,2): VGPR
// budget 256 (the LDS-implied occupancy), no chasing 4 waves/EU.
__global__ __attribute__((amdgpu_flat_work_group_size(256, 256),
                          amdgpu_waves_per_eu(2, 2))) void nf_policy_kernel(
    const float* __restrict__ x, const float* __restrict__ xs,
    const float* __restrict__ gW0, const float* __restrict__ gb0,
    const float* __restrict__ gW1, const float* __restrict__ gb1,
    const float* __restrict__ gW2, const float* __restrict__ gb2,
    float* __restrict__ out) {
  __shared__ __align__(16) f16x2 LW0[4096];  // [16p][4q][16m][4w] A-frags L1
  __shared__ __align__(16) f16x2 LW1[1024];  // [16p][2half][8row][4kk]
  __shared__ __align__(16) f16x2 LW2[4096];  // [16p][4b][16m][4kk(2 used)]
  __shared__ __align__(16) float LB0[256];   // [16p][16m]
  __shared__ __align__(16) float LB1[256];   // [16p][16m]
  __shared__ __align__(16) float LB2[1024];  // [16p][4b][16m]
  __shared__ __align__(16) float4 sHC[2048]; // [16p][128 active ln] H1H2 cache

  const int tid = threadIdx.x;
  // ---- stage weights: fp32 global -> f16 LDS in MFMA A-fragment order ----
  for (int i = tid; i < 4096; i += 256) {  // LW0
    const int p = i >> 8, rem = i & 255, qq = rem >> 6, rem2 = rem & 63;
    const int mm = rem2 >> 2, w = rem2 & 3;
    const int net = pbase(p) + (mm >> 3);
    const int h = mm & 7, k0 = qq * 8 + w * 2;
    const float* src = gW0 + net * 256 + h * 32 + k0;
    LW0[i] = pk(src[0], src[1]);
  }
  for (int i = tid; i < 1024; i += 256) {  // LW1
    const int p = i >> 6, rem = i & 63, half = rem >> 5;
    const int row = (rem >> 2) & 7, kk = rem & 3;
    const int net = pbase(p) + half;
    const float* src = gW1 + net * 64 + row * 8 + kk * 2;
    LW1[i] = pk(src[0], src[1]);
  }
  for (int i = tid; i < 4096; i += 256) {  // LW2 (rows permuted)
    const int p = i >> 8, rem = i & 255, b = rem >> 6, rem2 = rem & 63;
    const int mm = rem2 >> 2, kk = rem2 & 3;
    const int net = pbase(p) + (b >> 1);
    const int d = 8 * (mm >> 2) + ((b & 1) << 2) + (mm & 3);
    const float* src = gW2 + net * 256 + d * 8 + kk * 2;
    LW2[i] = pk(src[0], src[1]);
  }
  for (int i = tid; i < 256; i += 256) {  // LB0/LB1
    const int p = i >> 4, mm = i & 15;
    const int net = pbase(p) + (mm >> 3);
    LB0[i] = gb0[net * 8 + (mm & 7)];
    LB1[i] = gb1[net * 8 + (mm & 7)];
  }
  for (int i = tid; i < 1024; i += 256) {  // LB2 (permuted like LW2 rows)
    const int p = i >> 6, b = (i >> 4) & 3, mm = i & 15;
    const int net = pbase(p) + (b >> 1);
    const int d = 8 * (mm >> 2) + ((b & 1) << 2) + (mm & 3);
    LB2[i] = gb2[net * 32 + d];
  }
  __syncthreads();

  const int lane = tid & 63;
  const int wv = tid >> 6;
  const int n = lane & 15;   // MFMA col / A row role (lanes n>=8 mirror n-8)
  const int q = lane >> 4;   // quad: owns state dims 8q..8q+7
  const int e = blockIdx.x * 32 + wv * 8 + (n & 7);
  const int hcb = wv * 32 + q * 8 + (n & 7);  // compacted H-cache slot

  const v4h z4 = {(__fp16)0.f, (__fp16)0.f, (__fp16)0.f, (__fp16)0.f};
  const f32x4 zc = {0.f, 0.f, 0.f, 0.f};
  const bool act1 = (n < 8) == (q < 2);
  const int a1off = ((n & 7) << 2) + ((q & 1) << 1) + ((n >= 8) ? 32 : 0);
  const int abbase = n * 4 + ((q & 1) << 1);

  float lo0, lo1, lo2, lo3, lo4, lo5, lo6, lo7;
  float up0, up1, up2, up3, up4, up5, up6, up7;
  float av0, av1, av2, av3, av4, av5, av6, av7;
  float bv0, bv1, bv2, bv3, bv4, bv5, bv6, bv7;
  {
    const float* xe = x + (size_t)e * 64;
    const float* se = xs + (size_t)e * 64;
    const float4 a0 = *(const float4*)(xe + q * 8);
    const float4 a1 = *(const float4*)(xe + q * 8 + 4);
    const float4 u0 = *(const float4*)(xe + 32 + q * 8);
    const float4 u1 = *(const float4*)(xe + 32 + q * 8 + 4);
    const float4 p0 = *(const float4*)(se + q * 8);
    const float4 p1 = *(const float4*)(se + q * 8 + 4);
    const float4 r0 = *(const float4*)(se + 32 + q * 8);
    const float4 r1 = *(const float4*)(se + 32 + q * 8 + 4);
    lo0 = a0.x; lo1 = a0.y; lo2 = a0.z; lo3 = a0.w;
    lo4 = a1.x; lo5 = a1.y; lo6 = a1.z; lo7 = a1.w;
    up0 = u0.x; up1 = u0.y; up2 = u0.z; up3 = u0.w;
    up4 = u1.x; up5 = u1.y; up6 = u1.z; up7 = u1.w;
    av0 = -2.f * (a0.x - p0.x); av1 = -2.f * (a0.y - p0.y);
    av2 = -2.f * (a0.z - p0.z); av3 = -2.f * (a0.w - p0.w);
    av4 = -2.f * (a1.x - p1.x); av5 = -2.f * (a1.y - p1.y);
    av6 = -2.f * (a1.z - p1.z); av7 = -2.f * (a1.w - p1.w);
    bv0 = -2.f * (u0.x - r0.x); bv1 = -2.f * (u0.y - r0.y);
    bv2 = -2.f * (u0.z - r0.z); bv3 = -2.f * (u0.w - r0.w);
    bv4 = -2.f * (u1.x - r1.x); bv5 = -2.f * (u1.y - r1.y);
    bv6 = -2.f * (u1.z - r1.z); bv7 = -2.f * (u1.w - r1.w);
  }

  // ---------------- forward: z = phi(x); cache H1/H2 frags ---------------
  // even p: reads lo, updates up; odd p: reads up, updates lo.
#pragma unroll
  for (int st = 0; st < 8; ++st) {
    FWD_HALF(2 * st, lo, up);
    FWD_HALF(2 * st + 1, up, lo);
  }

  // ------------- backward: y = J^{-1} g, inverting the flow -------------
  // odd p first (it updated lo in fwd; its input dual is bv), then even p.
#pragma unroll
  for (int st = 7; st >= 0; --st) {
    BWD_HALF(2 * st + 1, lo, av, bv);
    BWD_HALF(2 * st, up, bv, av);
  }

  if (n < 8) {
    float* oe = out + (size_t)e * 64;
    float4 v;
    v.x = av0; v.y = av1; v.z = av2; v.w = av3;
    *(float4*)(oe + q * 8) = v;
    v.x = av4; v.y = av5; v.z = av6; v.w = av7;
    *(float4*)(oe + q * 8 + 4) = v;
    v.x = bv0; v.y = bv1; v.z = bv2; v.w = bv3;
    *(float4*)(oe + 32 + q * 8) = v;
    v.x = bv4; v.y = bv5; v.z = bv6; v.w = bv7;
    *(float4*)(oe + 32 + q * 8 + 4) = v;
  }
}

extern "C" void kernel_launch(void* const* d_in, const int* in_sizes, int n_in,
                              void* d_out, int out_size, void* d_ws,
                              size_t ws_size, hipStream_t stream) {
  const float* x  = (const float*)d_in[0];
  const float* xs = (const float*)d_in[1];
  const float* W0 = (const float*)d_in[2];
  const float* b0 = (const float*)d_in[3];
  const float* W1 = (const float*)d_in[4];
  const float* b1 = (const float*)d_in[5];
  const float* W2 = (const float*)d_in[6];
  const float* b2 = (const float*)d_in[7];
  float* out = (float*)d_out;

  dim3 grid(NB / 32);  // 512 blocks, 32 elements each (8 per wave, mirrored)
  dim3 block(256);
  nf_policy_kernel<<<grid, block, 0, stream>>>(x, xs, W0, b0, W1, b1, W2, b2,
                                               out);
}

// Round 6
// 103.138 us; speedup vs baseline: 1.0131x; 1.0131x over previous
//
#include <hip/hip_runtime.h>

// B=16384, DIM=64, 8 coupling steps, H=8, D2=32.
// y = J^{-1} g applied analytically (triangular coupling blocks -> MLP JVPs);
// intermediate states recovered by inverting the flow from z = phi(x).
//
// R16 = R15 with the LAST aggregate locals (U8/U4 unions) eliminated.
// R15 scalarized all float arrays but WRITE_SIZE only dropped 27->25 MB and
// dur stayed 43 us: the unions (Bq/H1/H2/Bu/G1/G2, 2x per half-step) store
// through an ARRAY member (h[0..3]) then load the whole object at a
// DIFFERENT type (.v, <8 x half>) -- mixed-type overlapping slices defeat
// SROA -> allocas -> scratch store->dependent-load round-trips ON the serial
// 32-half-step chain (explains the ~80K stall cycles/SIMD and the ~21 MB
// phantom WRITE_SIZE from L2 evictions of hot stack slots).
// R16 builds MFMA operands in pure SSA: f16x2 named values + initializer-
// list u32 vectors + __builtin_bit_cast (insertelement/bitcast in IR, no
// memory). Zero aggregate locals remain anywhere in the kernel body.
// Layout identity (gfx950, verified m89): D (col=lane&15,row=4q+reg) ==
// B-operand (n=lane&15,k=4q+j) for K=16 -> tanh(D)->pack is per-lane, zero
// cross-lane ops.

namespace {

typedef __fp16 f16x2 __attribute__((ext_vector_type(2)));
typedef __fp16 v4h __attribute__((ext_vector_type(4)));
typedef __fp16 v8h __attribute__((ext_vector_type(8)));
typedef float f32x4 __attribute__((ext_vector_type(4)));
typedef unsigned int u32;
typedef u32 u32x2 __attribute__((ext_vector_type(2)));
typedef u32 u32x4 __attribute__((ext_vector_type(4)));

constexpr int NB = 16384;

__device__ __forceinline__ float frcp(float x) { return __builtin_amdgcn_rcpf(x); }
__device__ __forceinline__ float ftanh(float x) {
  float e = __expf(2.f * x);
  return 1.f - 2.f * frcp(e + 1.f);
}
__device__ __forceinline__ f16x2 pk(float a, float b) {
  return __builtin_amdgcn_cvt_pkrtz(a, b);
}
// Pure-SSA operand assembly: initializer-list vectors + bitcast, no memory.
__device__ __forceinline__ v8h mk8(f16x2 a, f16x2 b, f16x2 c, f16x2 d) {
  const u32x4 t = {__builtin_bit_cast(u32, a), __builtin_bit_cast(u32, b),
                   __builtin_bit_cast(u32, c), __builtin_bit_cast(u32, d)};
  return __builtin_bit_cast(v8h, t);
}
__device__ __forceinline__ v4h mk4(f16x2 a, f16x2 b) {
  const u32x2 t = {__builtin_bit_cast(u32, a), __builtin_bit_cast(u32, b)};
  return __builtin_bit_cast(v4h, t);
}

// net pair p (0..15): step i = p>>1, half = p&1 -> t-net base.
__device__ __forceinline__ int pbase(int p) {
  return ((p >> 1) << 2) + ((p & 1) << 1);
}

}  // namespace

// ---- forward L3 block: one output quad -> four named scalars ----
#define L3_FWD(P, BB, D0, D1, D2, D3)                                         \
  do {                                                                        \
    const bool act_ = ((BB) < 2) == (q < 2);                                  \
    v4h Ab = *(const v4h*)(LW2 + ((P)*256 + (BB)*64 + abbase));               \
    Ab = act_ ? Ab : z4;                                                      \
    const f32x4 cb = *(const f32x4*)(LB2 + ((P)*4 + (BB)) * 16 + q * 4);      \
    const f32x4 ob =                                                          \
        __builtin_amdgcn_mfma_f32_16x16x16f16(Ab, H2v, cb, 0, 0, 0);          \
    D0 = ob[0]; D1 = ob[1]; D2 = ob[2]; D3 = ob[3];                           \
  } while (0)

#define FWD_UPD(J, W) W##J = fmaf(W##J, __expf(s##J), t##J)

// ---- forward half-step P: reads V0..V7 (prefix V), updates W0..W7 ----
#define FWD_HALF(P, V, W)                                                     \
  do {                                                                        \
    const v8h Bq = mk8(pk(V##0, V##1), pk(V##2, V##3), pk(V##4, V##5),        \
                       pk(V##6, V##7));                                       \
    const v8h A0 = *(const v8h*)(LW0 + (((P)*64 + q * 16 + n) << 2));         \
    const f32x4 c0 = *(const f32x4*)(LB0 + (P)*16 + q * 4);                   \
    f32x4 d1 = __builtin_amdgcn_mfma_f32_16x16x32_f16(A0, Bq, c0, 0, 0, 0);   \
    const f16x2 H1a = pk(ftanh(d1[0]), ftanh(d1[1]));                         \
    const f16x2 H1b = pk(ftanh(d1[2]), ftanh(d1[3]));                         \
    v4h A1 = *(const v4h*)(LW1 + ((P)*64 + a1off));                           \
    A1 = act1 ? A1 : z4;                                                      \
    const f32x4 c1 = *(const f32x4*)(LB1 + (P)*16 + q * 4);                   \
    f32x4 d2 =                                                                \
        __builtin_amdgcn_mfma_f32_16x16x16f16(A1, mk4(H1a, H1b), c1, 0, 0, 0);\
    const f16x2 H2a = pk(ftanh(d2[0]), ftanh(d2[1]));                         \
    const f16x2 H2b = pk(ftanh(d2[2]), ftanh(d2[3]));                         \
    const v4h H2v = mk4(H2a, H2b);                                            \
    if (n < 8) {                                                              \
      const float4 pkd = {__builtin_bit_cast(float, H1a),                     \
                          __builtin_bit_cast(float, H1b),                     \
                          __builtin_bit_cast(float, H2a),                     \
                          __builtin_bit_cast(float, H2b)};                    \
      sHC[(P)*128 + hcb] = pkd;                                               \
    }                                                                         \
    float t0, t1, t2, t3, t4, t5, t6, t7;                                     \
    float s0, s1, s2, s3, s4, s5, s6, s7;                                     \
    L3_FWD(P, 0, t0, t1, t2, t3);                                             \
    L3_FWD(P, 1, t4, t5, t6, t7);                                             \
    L3_FWD(P, 2, s0, s1, s2, s3);                                             \
    L3_FWD(P, 3, s4, s5, s6, s7);                                             \
    FWD_UPD(0, W); FWD_UPD(1, W); FWD_UPD(2, W); FWD_UPD(3, W);               \
    FWD_UPD(4, W); FWD_UPD(5, W); FWD_UPD(6, W); FWD_UPD(7, W);               \
  } while (0)

// ---- backward L3 block: t/s recompute + JVP -> eight named scalars ----
#define L3_BWD(P, BB, D0, D1, D2, D3, J0, J1, J2, J3)                         \
  do {                                                                        \
    const bool act_ = ((BB) < 2) == (q < 2);                                  \
    v4h Ab = *(const v4h*)(LW2 + ((P)*256 + (BB)*64 + abbase));               \
    Ab = act_ ? Ab : z4;                                                      \
    const f32x4 cb = *(const f32x4*)(LB2 + ((P)*4 + (BB)) * 16 + q * 4);      \
    const f32x4 ob =                                                          \
        __builtin_amdgcn_mfma_f32_16x16x16f16(Ab, H2v, cb, 0, 0, 0);          \
    const f32x4 jb =                                                          \
        __builtin_amdgcn_mfma_f32_16x16x16f16(Ab, G2v, zc, 0, 0, 0);          \
    D0 = ob[0]; D1 = ob[1]; D2 = ob[2]; D3 = ob[3];                           \
    J0 = jb[0]; J1 = jb[1]; J2 = jb[2]; J3 = jb[3];                           \
  } while (0)

#define BWD_INV(J, ST, DME)                                                   \
  do {                                                                        \
    const float esi_ = __expf(-s##J);                                         \
    const float dd_ = ST##J - t##J;                                           \
    ST##J = dd_ * esi_;                                                       \
    DME##J = (DME##J - ut##J - dd_ * us##J) * esi_;                           \
  } while (0)

// ---- backward half-step P: inverts ST0..7, updates duals DME0..7 from DOT ----
#define BWD_HALF(P, ST, DME, DOT)                                             \
  do {                                                                        \
    const float4 pkd = sHC[(P)*128 + hcb];                                    \
    const f16x2 H1a = __builtin_bit_cast(f16x2, pkd.x);                       \
    const f16x2 H1b = __builtin_bit_cast(f16x2, pkd.y);                       \
    const f16x2 H2a = __builtin_bit_cast(f16x2, pkd.z);                       \
    const f16x2 H2b = __builtin_bit_cast(f16x2, pkd.w);                       \
    const v8h Bu = mk8(pk(DOT##0, DOT##1), pk(DOT##2, DOT##3),                \
                       pk(DOT##4, DOT##5), pk(DOT##6, DOT##7));               \
    const v8h A0 = *(const v8h*)(LW0 + (((P)*64 + q * 16 + n) << 2));         \
    f32x4 d1u = __builtin_amdgcn_mfma_f32_16x16x32_f16(A0, Bu, zc, 0, 0, 0);  \
    const float h10 = (float)H1a[0], h11 = (float)H1a[1];                     \
    const float h12 = (float)H1b[0], h13 = (float)H1b[1];                     \
    const f16x2 G1a =                                                         \
        pk((1.f - h10 * h10) * d1u[0], (1.f - h11 * h11) * d1u[1]);           \
    const f16x2 G1b =                                                         \
        pk((1.f - h12 * h12) * d1u[2], (1.f - h13 * h13) * d1u[3]);           \
    v4h A1 = *(const v4h*)(LW1 + ((P)*64 + a1off));                           \
    A1 = act1 ? A1 : z4;                                                      \
    f32x4 d2u =                                                               \
        __builtin_amdgcn_mfma_f32_16x16x16f16(A1, mk4(G1a, G1b), zc, 0, 0, 0);\
    const float h20 = (float)H2a[0], h21 = (float)H2a[1];                     \
    const float h22 = (float)H2b[0], h23 = (float)H2b[1];                     \
    const f16x2 G2a =                                                         \
        pk((1.f - h20 * h20) * d2u[0], (1.f - h21 * h21) * d2u[1]);           \
    const f16x2 G2b =                                                         \
        pk((1.f - h22 * h22) * d2u[2], (1.f - h23 * h23) * d2u[3]);           \
    const v4h H2v = mk4(H2a, H2b);                                            \
    const v4h G2v = mk4(G2a, G2b);                                            \
    float t0, t1, t2, t3, t4, t5, t6, t7;                                     \
    float s0, s1, s2, s3, s4, s5, s6, s7;                                     \
    float ut0, ut1, ut2, ut3, ut4, ut5, ut6, ut7;                             \
    float us0, us1, us2, us3, us4, us5, us6, us7;                             \
    L3_BWD(P, 0, t0, t1, t2, t3, ut0, ut1, ut2, ut3);                         \
    L3_BWD(P, 1, t4, t5, t6, t7, ut4, ut5, ut6, ut7);                         \
    L3_BWD(P, 2, s0, s1, s2, s3, us0, us1, us2, us3);                         \
    L3_BWD(P, 3, s4, s5, s6, s7, us4, us5, us6, us7);                         \
    BWD_INV(0, ST, DME); BWD_INV(1, ST, DME);                                 \
    BWD_INV(2, ST, DME); BWD_INV(3, ST, DME);                                 \
    BWD_INV(4, ST, DME); BWD_INV(5, ST, DME);                                 \
    BWD_INV(6, ST, DME); BWD_INV(7, ST, DME);                                 \
  } while (0)

// 256 threads = 4 waves = 32 elements/block (8/wave, mirrored), grid 512 ->
// 2048 waves = 2/SIMD, 2 blocks/CU. LDS: 42 KiB weights + 32 KiB H-cache =
// 74 KiB (<80 KiB so two blocks co-reside). waves_per_eu pinned (2,2): VGPR
// budget 256 (the LDS-implied occupancy), no chasing 4 waves/EU.
__global__ __attribute__((amdgpu_flat_work_group_size(256, 256),
                          amdgpu_waves_per_eu(2, 2))) void nf_policy_kernel(
    const float* __restrict__ x, const float* __restrict__ xs,
    const float* __restrict__ gW0, const float* __restrict__ gb0,
    const float* __restrict__ gW1, const float* __restrict__ gb1,
    const float* __restrict__ gW2, const float* __restrict__ gb2,
    float* __restrict__ out) {
  __shared__ __align__(16) f16x2 LW0[4096];  // [16p][4q][16m][4w] A-frags L1
  __shared__ __align__(16) f16x2 LW1[1024];  // [16p][2half][8row][4kk]
  __shared__ __align__(16) f16x2 LW2[4096];  // [16p][4b][16m][4kk(2 used)]
  __shared__ __align__(16) float LB0[256];   // [16p][16m]
  __shared__ __align__(16) float LB1[256];   // [16p][16m]
  __shared__ __align__(16) float LB2[1024];  // [16p][4b][16m]
  __shared__ __align__(16) float4 sHC[2048]; // [16p][128 active ln] H1H2 cache

  const int tid = threadIdx.x;
  // ---- stage weights: fp32 global -> f16 LDS in MFMA A-fragment order ----
  for (int i = tid; i < 4096; i += 256) {  // LW0
    const int p = i >> 8, rem = i & 255, qq = rem >> 6, rem2 = rem & 63;
    const int mm = rem2 >> 2, w = rem2 & 3;
    const int net = pbase(p) + (mm >> 3);
    const int h = mm & 7, k0 = qq * 8 + w * 2;
    const float* src = gW0 + net * 256 + h * 32 + k0;
    LW0[i] = pk(src[0], src[1]);
  }
  for (int i = tid; i < 1024; i += 256) {  // LW1
    const int p = i >> 6, rem = i & 63, half = rem >> 5;
    const int row = (rem >> 2) & 7, kk = rem & 3;
    const int net = pbase(p) + half;
    const float* src = gW1 + net * 64 + row * 8 + kk * 2;
    LW1[i] = pk(src[0], src[1]);
  }
  for (int i = tid; i < 4096; i += 256) {  // LW2 (rows permuted)
    const int p = i >> 8, rem = i & 255, b = rem >> 6, rem2 = rem & 63;
    const int mm = rem2 >> 2, kk = rem2 & 3;
    const int net = pbase(p) + (b >> 1);
    const int d = 8 * (mm >> 2) + ((b & 1) << 2) + (mm & 3);
    const float* src = gW2 + net * 256 + d * 8 + kk * 2;
    LW2[i] = pk(src[0], src[1]);
  }
  for (int i = tid; i < 256; i += 256) {  // LB0/LB1
    const int p = i >> 4, mm = i & 15;
    const int net = pbase(p) + (mm >> 3);
    LB0[i] = gb0[net * 8 + (mm & 7)];
    LB1[i] = gb1[net * 8 + (mm & 7)];
  }
  for (int i = tid; i < 1024; i += 256) {  // LB2 (permuted like LW2 rows)
    const int p = i >> 6, b = (i >> 4) & 3, mm = i & 15;
    const int net = pbase(p) + (b >> 1);
    const int d = 8 * (mm >> 2) + ((b & 1) << 2) + (mm & 3);
    LB2[i] = gb2[net * 32 + d];
  }
  __syncthreads();

  const int lane = tid & 63;
  const int wv = tid >> 6;
  const int n = lane & 15;   // MFMA col / A row role (lanes n>=8 mirror n-8)
  const int q = lane >> 4;   // quad: owns state dims 8q..8q+7
  const int e = blockIdx.x * 32 + wv * 8 + (n & 7);
  const int hcb = wv * 32 + q * 8 + (n & 7);  // compacted H-cache slot

  const v4h z4 = {(__fp16)0.f, (__fp16)0.f, (__fp16)0.f, (__fp16)0.f};
  const f32x4 zc = {0.f, 0.f, 0.f, 0.f};
  const bool act1 = (n < 8) == (q < 2);
  const int a1off = ((n & 7) << 2) + ((q & 1) << 1) + ((n >= 8) ? 32 : 0);
  const int abbase = n * 4 + ((q & 1) << 1);

  float lo0, lo1, lo2, lo3, lo4, lo5, lo6, lo7;
  float up0, up1, up2, up3, up4, up5, up6, up7;
  float av0, av1, av2, av3, av4, av5, av6, av7;
  float bv0, bv1, bv2, bv3, bv4, bv5, bv6, bv7;
  {
    const float* xe = x + (size_t)e * 64;
    const float* se = xs + (size_t)e * 64;
    const float4 a0 = *(const float4*)(xe + q * 8);
    const float4 a1 = *(const float4*)(xe + q * 8 + 4);
    const float4 u0 = *(const float4*)(xe + 32 + q * 8);
    const float4 u1 = *(const float4*)(xe + 32 + q * 8 + 4);
    const float4 p0 = *(const float4*)(se + q * 8);
    const float4 p1 = *(const float4*)(se + q * 8 + 4);
    const float4 r0 = *(const float4*)(se + 32 + q * 8);
    const float4 r1 = *(const float4*)(se + 32 + q * 8 + 4);
    lo0 = a0.x; lo1 = a0.y; lo2 = a0.z; lo3 = a0.w;
    lo4 = a1.x; lo5 = a1.y; lo6 = a1.z; lo7 = a1.w;
    up0 = u0.x; up1 = u0.y; up2 = u0.z; up3 = u0.w;
    up4 = u1.x; up5 = u1.y; up6 = u1.z; up7 = u1.w;
    av0 = -2.f * (a0.x - p0.x); av1 = -2.f * (a0.y - p0.y);
    av2 = -2.f * (a0.z - p0.z); av3 = -2.f * (a0.w - p0.w);
    av4 = -2.f * (a1.x - p1.x); av5 = -2.f * (a1.y - p1.y);
    av6 = -2.f * (a1.z - p1.z); av7 = -2.f * (a1.w - p1.w);
    bv0 = -2.f * (u0.x - r0.x); bv1 = -2.f * (u0.y - r0.y);
    bv2 = -2.f * (u0.z - r0.z); bv3 = -2.f * (u0.w - r0.w);
    bv4 = -2.f * (u1.x - r1.x); bv5 = -2.f * (u1.y - r1.y);
    bv6 = -2.f * (u1.z - r1.z); bv7 = -2.f * (u1.w - r1.w);
  }

  // ---------------- forward: z = phi(x); cache H1/H2 frags ---------------
  // even p: reads lo, updates up; odd p: reads up, updates lo.
#pragma unroll
  for (int st = 0; st < 8; ++st) {
    FWD_HALF(2 * st, lo, up);
    FWD_HALF(2 * st + 1, up, lo);
  }

  // ------------- backward: y = J^{-1} g, inverting the flow -------------
  // odd p first (it updated lo in fwd; its input dual is bv), then even p.
#pragma unroll
  for (int st = 7; st >= 0; --st) {
    BWD_HALF(2 * st + 1, lo, av, bv);
    BWD_HALF(2 * st, up, bv, av);
  }

  if (n < 8) {
    float* oe = out + (size_t)e * 64;
    float4 v;
    v.x = av0; v.y = av1; v.z = av2; v.w = av3;
    *(float4*)(oe + q * 8) = v;
    v.x = av4; v.y = av5; v.z = av6; v.w = av7;
    *(float4*)(oe + q * 8 + 4) = v;
    v.x = bv0; v.y = bv1; v.z = bv2; v.w = bv3;
    *(float4*)(oe + 32 + q * 8) = v;
    v.x = bv4; v.y = bv5; v.z = bv6; v.w = bv7;
    *(float4*)(oe + 32 + q * 8 + 4) = v;
  }
}

extern "C" void kernel_launch(void* const* d_in, const int* in_sizes, int n_in,
                              void* d_out, int out_size, void* d_ws,
                              size_t ws_size, hipStream_t stream) {
  const float* x  = (const float*)d_in[0];
  const float* xs = (const float*)d_in[1];
  const float* W0 = (const float*)d_in[2];
  const float* b0 = (const float*)d_in[3];
  const float* W1 = (const float*)d_in[4];
  const float* b1 = (const float*)d_in[5];
  const float* W2 = (const float*)d_in[6];
  const float* b2 = (const float*)d_in[7];
  float* out = (float*)d_out;

  dim3 grid(NB / 32);  // 512 blocks, 32 elements each (8 per wave, mirrored)
  dim3 block(256);
  nf_policy_kernel<<<grid, block, 0, stream>>>(x, xs, W0, b0, W1, b1, W2, b2,
                                               out);
}

// Round 7
// 98.923 us; speedup vs baseline: 1.0562x; 1.0426x over previous
//
#include <hip/hip_runtime.h>

// B=16384, DIM=64, 8 coupling steps, H=8, D2=32.
// y = J^{-1} g applied analytically (triangular coupling blocks -> MLP JVPs);
// intermediate states recovered by inverting the flow from z = phi(x).
//
// R17 = R16 RE-ROLLED. R14-R16 eliminated scratch allocas step by step
// (WRITE_SIZE 32->21.5 MB) yet dur_us never moved from ~43 us: the phantom
// traffic was asynchronous, never on the critical path. Issue accounting at
// 43 us shows ~55% of cycles with NOTHING issuing (VALU 28 + MFMA 7 + ~10
// LDS/SALU), VGPR=128 unpressured, banks/HBM idle -> instruction front-end.
// The fully-unrolled 32-half-step body is O(150+ KB) of straight-line text
// executed ONCE per wave vs 32 KB L1 I$: zero code reuse, continuous I$
// miss streaming from L2, stalls land on the serial chain. (FETCH_SIZE
// excess tracked code size across R14->R16 = code fetched ~once per XCD.)
// R17 rolls fwd/bwd into unroll(disable) loops (2 half-steps/iter, runtime
// p): body ~3-4 KB, total text ~12 KB -> fits I$, reused 8x. LDS addressing
// is register-based; runtime p costs 2 adds per operand block.
// Layout identity (gfx950, verified m89): D (col=lane&15,row=4q+reg) ==
// B-operand (n=lane&15,k=4q+j) for K=16 -> tanh(D)->pack is per-lane, zero
// cross-lane ops.

namespace {

typedef __fp16 f16x2 __attribute__((ext_vector_type(2)));
typedef __fp16 v4h __attribute__((ext_vector_type(4)));
typedef __fp16 v8h __attribute__((ext_vector_type(8)));
typedef float f32x4 __attribute__((ext_vector_type(4)));
typedef unsigned int u32;
typedef u32 u32x2 __attribute__((ext_vector_type(2)));
typedef u32 u32x4 __attribute__((ext_vector_type(4)));

constexpr int NB = 16384;

__device__ __forceinline__ float frcp(float x) { return __builtin_amdgcn_rcpf(x); }
__device__ __forceinline__ float ftanh(float x) {
  float e = __expf(2.f * x);
  return 1.f - 2.f * frcp(e + 1.f);
}
__device__ __forceinline__ f16x2 pk(float a, float b) {
  return __builtin_amdgcn_cvt_pkrtz(a, b);
}
// Pure-SSA operand assembly: initializer-list vectors + bitcast, no memory.
__device__ __forceinline__ v8h mk8(f16x2 a, f16x2 b, f16x2 c, f16x2 d) {
  const u32x4 t = {__builtin_bit_cast(u32, a), __builtin_bit_cast(u32, b),
                   __builtin_bit_cast(u32, c), __builtin_bit_cast(u32, d)};
  return __builtin_bit_cast(v8h, t);
}
__device__ __forceinline__ v4h mk4(f16x2 a, f16x2 b) {
  const u32x2 t = {__builtin_bit_cast(u32, a), __builtin_bit_cast(u32, b)};
  return __builtin_bit_cast(v4h, t);
}

// net pair p (0..15): step i = p>>1, half = p&1 -> t-net base.
__device__ __forceinline__ int pbase(int p) {
  return ((p >> 1) << 2) + ((p & 1) << 1);
}

}  // namespace

// ---- forward L3 block: one output quad -> four named scalars ----
#define L3_FWD(P, BB, D0, D1, D2, D3)                                         \
  do {                                                                        \
    const bool act_ = ((BB) < 2) == (q < 2);                                  \
    v4h Ab = *(const v4h*)(LW2 + ((P)*256 + (BB)*64 + abbase));               \
    Ab = act_ ? Ab : z4;                                                      \
    const f32x4 cb = *(const f32x4*)(LB2 + ((P)*4 + (BB)) * 16 + q * 4);      \
    const f32x4 ob =                                                          \
        __builtin_amdgcn_mfma_f32_16x16x16f16(Ab, H2v, cb, 0, 0, 0);          \
    D0 = ob[0]; D1 = ob[1]; D2 = ob[2]; D3 = ob[3];                           \
  } while (0)

#define FWD_UPD(J, W) W##J = fmaf(W##J, __expf(s##J), t##J)

// ---- forward half-step P: reads V0..V7 (prefix V), updates W0..W7 ----
#define FWD_HALF(P, V, W)                                                     \
  do {                                                                        \
    const v8h Bq = mk8(pk(V##0, V##1), pk(V##2, V##3), pk(V##4, V##5),        \
                       pk(V##6, V##7));                                       \
    const v8h A0 = *(const v8h*)(LW0 + (((P)*64 + q * 16 + n) << 2));         \
    const f32x4 c0 = *(const f32x4*)(LB0 + (P)*16 + q * 4);                   \
    f32x4 d1 = __builtin_amdgcn_mfma_f32_16x16x32_f16(A0, Bq, c0, 0, 0, 0);   \
    const f16x2 H1a = pk(ftanh(d1[0]), ftanh(d1[1]));                         \
    const f16x2 H1b = pk(ftanh(d1[2]), ftanh(d1[3]));                         \
    v4h A1 = *(const v4h*)(LW1 + ((P)*64 + a1off));                           \
    A1 = act1 ? A1 : z4;                                                      \
    const f32x4 c1 = *(const f32x4*)(LB1 + (P)*16 + q * 4);                   \
    f32x4 d2 =                                                                \
        __builtin_amdgcn_mfma_f32_16x16x16f16(A1, mk4(H1a, H1b), c1, 0, 0, 0);\
    const f16x2 H2a = pk(ftanh(d2[0]), ftanh(d2[1]));                         \
    const f16x2 H2b = pk(ftanh(d2[2]), ftanh(d2[3]));                         \
    const v4h H2v = mk4(H2a, H2b);                                            \
    if (n < 8) {                                                              \
      const float4 pkd = {__builtin_bit_cast(float, H1a),                     \
                          __builtin_bit_cast(float, H1b),                     \
                          __builtin_bit_cast(float, H2a),                     \
                          __builtin_bit_cast(float, H2b)};                    \
      sHC[(P)*128 + hcb] = pkd;                                               \
    }                                                                         \
    float t0, t1, t2, t3, t4, t5, t6, t7;                                     \
    float s0, s1, s2, s3, s4, s5, s6, s7;                                     \
    L3_FWD(P, 0, t0, t1, t2, t3);                                             \
    L3_FWD(P, 1, t4, t5, t6, t7);                                             \
    L3_FWD(P, 2, s0, s1, s2, s3);                                             \
    L3_FWD(P, 3, s4, s5, s6, s7);                                             \
    FWD_UPD(0, W); FWD_UPD(1, W); FWD_UPD(2, W); FWD_UPD(3, W);               \
    FWD_UPD(4, W); FWD_UPD(5, W); FWD_UPD(6, W); FWD_UPD(7, W);               \
  } while (0)

// ---- backward L3 block: t/s recompute + JVP -> eight named scalars ----
#define L3_BWD(P, BB, D0, D1, D2, D3, J0, J1, J2, J3)                         \
  do {                                                                        \
    const bool act_ = ((BB) < 2) == (q < 2);                                  \
    v4h Ab = *(const v4h*)(LW2 + ((P)*256 + (BB)*64 + abbase));               \
    Ab = act_ ? Ab : z4;                                                      \
    const f32x4 cb = *(const f32x4*)(LB2 + ((P)*4 + (BB)) * 16 + q * 4);      \
    const f32x4 ob =                                                          \
        __builtin_amdgcn_mfma_f32_16x16x16f16(Ab, H2v, cb, 0, 0, 0);          \
    const f32x4 jb =                                                          \
        __builtin_amdgcn_mfma_f32_16x16x16f16(Ab, G2v, zc, 0, 0, 0);          \
    D0 = ob[0]; D1 = ob[1]; D2 = ob[2]; D3 = ob[3];                           \
    J0 = jb[0]; J1 = jb[1]; J2 = jb[2]; J3 = jb[3];                           \
  } while (0)

#define BWD_INV(J, ST, DME)                                                   \
  do {                                                                        \
    const float esi_ = __expf(-s##J);                                         \
    const float dd_ = ST##J - t##J;                                           \
    ST##J = dd_ * esi_;                                                       \
    DME##J = (DME##J - ut##J - dd_ * us##J) * esi_;                           \
  } while (0)

// ---- backward half-step P: inverts ST0..7, updates duals DME0..7 from DOT ----
#define BWD_HALF(P, ST, DME, DOT)                                             \
  do {                                                                        \
    const float4 pkd = sHC[(P)*128 + hcb];                                    \
    const f16x2 H1a = __builtin_bit_cast(f16x2, pkd.x);                       \
    const f16x2 H1b = __builtin_bit_cast(f16x2, pkd.y);                       \
    const f16x2 H2a = __builtin_bit_cast(f16x2, pkd.z);                       \
    const f16x2 H2b = __builtin_bit_cast(f16x2, pkd.w);                       \
    const v8h Bu = mk8(pk(DOT##0, DOT##1), pk(DOT##2, DOT##3),                \
                       pk(DOT##4, DOT##5), pk(DOT##6, DOT##7));               \
    const v8h A0 = *(const v8h*)(LW0 + (((P)*64 + q * 16 + n) << 2));         \
    f32x4 d1u = __builtin_amdgcn_mfma_f32_16x16x32_f16(A0, Bu, zc, 0, 0, 0);  \
    const float h10 = (float)H1a[0], h11 = (float)H1a[1];                     \
    const float h12 = (float)H1b[0], h13 = (float)H1b[1];                     \
    const f16x2 G1a =                                                         \
        pk((1.f - h10 * h10) * d1u[0], (1.f - h11 * h11) * d1u[1]);           \
    const f16x2 G1b =                                                         \
        pk((1.f - h12 * h12) * d1u[2], (1.f - h13 * h13) * d1u[3]);           \
    v4h A1 = *(const v4h*)(LW1 + ((P)*64 + a1off));                           \
    A1 = act1 ? A1 : z4;                                                      \
    f32x4 d2u =                                                               \
        __builtin_amdgcn_mfma_f32_16x16x16f16(A1, mk4(G1a, G1b), zc, 0, 0, 0);\
    const float h20 = (float)H2a[0], h21 = (float)H2a[1];                     \
    const float h22 = (float)H2b[0], h23 = (float)H2b[1];                     \
    const f16x2 G2a =                                                         \
        pk((1.f - h20 * h20) * d2u[0], (1.f - h21 * h21) * d2u[1]);           \
    const f16x2 G2b =                                                         \
        pk((1.f - h22 * h22) * d2u[2], (1.f - h23 * h23) * d2u[3]);           \
    const v4h H2v = mk4(H2a, H2b);                                            \
    const v4h G2v = mk4(G2a, G2b);                                            \
    float t0, t1, t2, t3, t4, t5, t6, t7;                                     \
    float s0, s1, s2, s3, s4, s5, s6, s7;                                     \
    float ut0, ut1, ut2, ut3, ut4, ut5, ut6, ut7;                             \
    float us0, us1, us2, us3, us4, us5, us6, us7;                             \
    L3_BWD(P, 0, t0, t1, t2, t3, ut0, ut1, ut2, ut3);                         \
    L3_BWD(P, 1, t4, t5, t6, t7, ut4, ut5, ut6, ut7);                         \
    L3_BWD(P, 2, s0, s1, s2, s3, us0, us1, us2, us3);                         \
    L3_BWD(P, 3, s4, s5, s6, s7, us4, us5, us6, us7);                         \
    BWD_INV(0, ST, DME); BWD_INV(1, ST, DME);                                 \
    BWD_INV(2, ST, DME); BWD_INV(3, ST, DME);                                 \
    BWD_INV(4, ST, DME); BWD_INV(5, ST, DME);                                 \
    BWD_INV(6, ST, DME); BWD_INV(7, ST, DME);                                 \
  } while (0)

// 256 threads = 4 waves = 32 elements/block (8/wave, mirrored), grid 512 ->
// 2048 waves = 2/SIMD, 2 blocks/CU. LDS: 42 KiB weights + 32 KiB H-cache =
// 74 KiB (<80 KiB so two blocks co-reside). waves_per_eu pinned (2,2): VGPR
// budget 256 (the LDS-implied occupancy), no chasing 4 waves/EU.
__global__ __attribute__((amdgpu_flat_work_group_size(256, 256),
                          amdgpu_waves_per_eu(2, 2))) void nf_policy_kernel(
    const float* __restrict__ x, const float* __restrict__ xs,
    const float* __restrict__ gW0, const float* __restrict__ gb0,
    const float* __restrict__ gW1, const float* __restrict__ gb1,
    const float* __restrict__ gW2, const float* __restrict__ gb2,
    float* __restrict__ out) {
  __shared__ __align__(16) f16x2 LW0[4096];  // [16p][4q][16m][4w] A-frags L1
  __shared__ __align__(16) f16x2 LW1[1024];  // [16p][2half][8row][4kk]
  __shared__ __align__(16) f16x2 LW2[4096];  // [16p][4b][16m][4kk(2 used)]
  __shared__ __align__(16) float LB0[256];   // [16p][16m]
  __shared__ __align__(16) float LB1[256];   // [16p][16m]
  __shared__ __align__(16) float LB2[1024];  // [16p][4b][16m]
  __shared__ __align__(16) float4 sHC[2048]; // [16p][128 active ln] H1H2 cache

  const int tid = threadIdx.x;
  // ---- stage weights: fp32 global -> f16 LDS in MFMA A-fragment order ----
  for (int i = tid; i < 4096; i += 256) {  // LW0
    const int p = i >> 8, rem = i & 255, qq = rem >> 6, rem2 = rem & 63;
    const int mm = rem2 >> 2, w = rem2 & 3;
    const int net = pbase(p) + (mm >> 3);
    const int h = mm & 7, k0 = qq * 8 + w * 2;
    const float* src = gW0 + net * 256 + h * 32 + k0;
    LW0[i] = pk(src[0], src[1]);
  }
  for (int i = tid; i < 1024; i += 256) {  // LW1
    const int p = i >> 6, rem = i & 63, half = rem >> 5;
    const int row = (rem >> 2) & 7, kk = rem & 3;
    const int net = pbase(p) + half;
    const float* src = gW1 + net * 64 + row * 8 + kk * 2;
    LW1[i] = pk(src[0], src[1]);
  }
  for (int i = tid; i < 4096; i += 256) {  // LW2 (rows permuted)
    const int p = i >> 8, rem = i & 255, b = rem >> 6, rem2 = rem & 63;
    const int mm = rem2 >> 2, kk = rem2 & 3;
    const int net = pbase(p) + (b >> 1);
    const int d = 8 * (mm >> 2) + ((b & 1) << 2) + (mm & 3);
    const float* src = gW2 + net * 256 + d * 8 + kk * 2;
    LW2[i] = pk(src[0], src[1]);
  }
  for (int i = tid; i < 256; i += 256) {  // LB0/LB1
    const int p = i >> 4, mm = i & 15;
    const int net = pbase(p) + (mm >> 3);
    LB0[i] = gb0[net * 8 + (mm & 7)];
    LB1[i] = gb1[net * 8 + (mm & 7)];
  }
  for (int i = tid; i < 1024; i += 256) {  // LB2 (permuted like LW2 rows)
    const int p = i >> 6, b = (i >> 4) & 3, mm = i & 15;
    const int net = pbase(p) + (b >> 1);
    const int d = 8 * (mm >> 2) + ((b & 1) << 2) + (mm & 3);
    LB2[i] = gb2[net * 32 + d];
  }
  __syncthreads();

  const int lane = tid & 63;
  const int wv = tid >> 6;
  const int n = lane & 15;   // MFMA col / A row role (lanes n>=8 mirror n-8)
  const int q = lane >> 4;   // quad: owns state dims 8q..8q+7
  const int e = blockIdx.x * 32 + wv * 8 + (n & 7);
  const int hcb = wv * 32 + q * 8 + (n & 7);  // compacted H-cache slot

  const v4h z4 = {(__fp16)0.f, (__fp16)0.f, (__fp16)0.f, (__fp16)0.f};
  const f32x4 zc = {0.f, 0.f, 0.f, 0.f};
  const bool act1 = (n < 8) == (q < 2);
  const int a1off = ((n & 7) << 2) + ((q & 1) << 1) + ((n >= 8) ? 32 : 0);
  const int abbase = n * 4 + ((q & 1) << 1);

  float lo0, lo1, lo2, lo3, lo4, lo5, lo6, lo7;
  float up0, up1, up2, up3, up4, up5, up6, up7;
  float av0, av1, av2, av3, av4, av5, av6, av7;
  float bv0, bv1, bv2, bv3, bv4, bv5, bv6, bv7;
  {
    const float* xe = x + (size_t)e * 64;
    const float* se = xs + (size_t)e * 64;
    const float4 a0 = *(const float4*)(xe + q * 8);
    const float4 a1 = *(const float4*)(xe + q * 8 + 4);
    const float4 u0 = *(const float4*)(xe + 32 + q * 8);
    const float4 u1 = *(const float4*)(xe + 32 + q * 8 + 4);
    const float4 p0 = *(const float4*)(se + q * 8);
    const float4 p1 = *(const float4*)(se + q * 8 + 4);
    const float4 r0 = *(const float4*)(se + 32 + q * 8);
    const float4 r1 = *(const float4*)(se + 32 + q * 8 + 4);
    lo0 = a0.x; lo1 = a0.y; lo2 = a0.z; lo3 = a0.w;
    lo4 = a1.x; lo5 = a1.y; lo6 = a1.z; lo7 = a1.w;
    up0 = u0.x; up1 = u0.y; up2 = u0.z; up3 = u0.w;
    up4 = u1.x; up5 = u1.y; up6 = u1.z; up7 = u1.w;
    av0 = -2.f * (a0.x - p0.x); av1 = -2.f * (a0.y - p0.y);
    av2 = -2.f * (a0.z - p0.z); av3 = -2.f * (a0.w - p0.w);
    av4 = -2.f * (a1.x - p1.x); av5 = -2.f * (a1.y - p1.y);
    av6 = -2.f * (a1.z - p1.z); av7 = -2.f * (a1.w - p1.w);
    bv0 = -2.f * (u0.x - r0.x); bv1 = -2.f * (u0.y - r0.y);
    bv2 = -2.f * (u0.z - r0.z); bv3 = -2.f * (u0.w - r0.w);
    bv4 = -2.f * (u1.x - r1.x); bv5 = -2.f * (u1.y - r1.y);
    bv6 = -2.f * (u1.z - r1.z); bv7 = -2.f * (u1.w - r1.w);
  }

  // ---------------- forward: z = phi(x); cache H1/H2 frags ---------------
  // even p: reads lo, updates up; odd p: reads up, updates lo.
  // ROLLED (unroll disabled): body ~2 half-steps, fits I$, reused 8x.
#pragma clang loop unroll(disable)
  for (int st = 0; st < 8; ++st) {
    const int p0i = 2 * st;
    FWD_HALF(p0i, lo, up);
    FWD_HALF(p0i + 1, up, lo);
  }

  // ------------- backward: y = J^{-1} g, inverting the flow -------------
  // odd p first (it updated lo in fwd; its input dual is bv), then even p.
#pragma clang loop unroll(disable)
  for (int st = 7; st >= 0; --st) {
    const int p0i = 2 * st;
    BWD_HALF(p0i + 1, lo, av, bv);
    BWD_HALF(p0i, up, bv, av);
  }

  if (n < 8) {
    float* oe = out + (size_t)e * 64;
    float4 v;
    v.x = av0; v.y = av1; v.z = av2; v.w = av3;
    *(float4*)(oe + q * 8) = v;
    v.x = av4; v.y = av5; v.z = av6; v.w = av7;
    *(float4*)(oe + q * 8 + 4) = v;
    v.x = bv0; v.y = bv1; v.z = bv2; v.w = bv3;
    *(float4*)(oe + 32 + q * 8) = v;
    v.x = bv4; v.y = bv5; v.z = bv6; v.w = bv7;
    *(float4*)(oe + 32 + q * 8 + 4) = v;
  }
}

extern "C" void kernel_launch(void* const* d_in, const int* in_sizes, int n_in,
                              void* d_out, int out_size, void* d_ws,
                              size_t ws_size, hipStream_t stream) {
  const float* x  = (const float*)d_in[0];
  const float* xs = (const float*)d_in[1];
  const float* W0 = (const float*)d_in[2];
  const float* b0 = (const float*)d_in[3];
  const float* W1 = (const float*)d_in[4];
  const float* b1 = (const float*)d_in[5];
  const float* W2 = (const float*)d_in[6];
  const float* b2 = (const float*)d_in[7];
  float* out = (float*)d_out;

  dim3 grid(NB / 32);  // 512 blocks, 32 elements each (8 per wave, mirrored)
  dim3 block(256);
  nf_policy_kernel<<<grid, block, 0, stream>>>(x, xs, W0, b0, W1, b1, W2, b2,
                                               out);
}